// Round 2
// baseline (243.821 us; speedup 1.0000x reference)
//
#include <hip/hip_runtime.h>
#include <math.h>

// Problem dims (fixed by the reference)
#define HDIM   2048
#define TWOH   4096
#define SEQLEN 8192
#define ROW_CHUNKS 32           // HDIM / 64 rows per chunk

// ---------------------------------------------------------------------------
// Kernel A: partial v = W^T * hidden.
// Grid (16, 32), block 256. Block (bx,by): columns e = bx*256+tx,
// rows h in [by*64, by*64+64). Writes partial[by][e].
// Lanes read consecutive e -> fully coalesced rows of W.
// ---------------------------------------------------------------------------
__global__ __launch_bounds__(256) void wtv_partial_kernel(
    const float* __restrict__ W, const float* __restrict__ hidden,
    float* __restrict__ partial)
{
    const int e  = blockIdx.x * 256 + threadIdx.x;   // 0..4095
    const int h0 = blockIdx.y * 64;
    float acc = 0.0f;
#pragma unroll
    for (int i = 0; i < 64; ++i) {
        const int h = h0 + i;
        acc = fmaf(W[(size_t)h * TWOH + e], hidden[h], acc);
    }
    partial[blockIdx.y * TWOH + e] = acc;
}

// ---------------------------------------------------------------------------
// Kernel B: v[e] = sum over 32 partials. Grid 16, block 256.
// ---------------------------------------------------------------------------
__global__ __launch_bounds__(256) void wtv_reduce_kernel(
    const float* __restrict__ partial, float* __restrict__ v)
{
    const int e = blockIdx.x * 256 + threadIdx.x;
    float acc = 0.0f;
#pragma unroll
    for (int p = 0; p < ROW_CHUNKS; ++p)
        acc += partial[p * TWOH + e];
    v[e] = acc;
}

// ---------------------------------------------------------------------------
// Kernel C: scores[r] = enc[r] . v   (row dot of length 4096)
// Grid 2048 blocks x 256 threads (4 waves); one wave per row.
// v staged in LDS as float4 (2-way bank aliasing only -> free).
// ---------------------------------------------------------------------------
__global__ __launch_bounds__(256) void scores_kernel(
    const float* __restrict__ enc, const float* __restrict__ v,
    float* __restrict__ scores)
{
    __shared__ float4 vs[TWOH / 4];                  // 16 KiB
    const float4* v4 = reinterpret_cast<const float4*>(v);
    for (int i = threadIdx.x; i < TWOH / 4; i += 256)
        vs[i] = v4[i];
    __syncthreads();

    const int wave = threadIdx.x >> 6;
    const int lane = threadIdx.x & 63;
    const int r    = blockIdx.x * 4 + wave;          // 0..8191

    const float4* e4 = reinterpret_cast<const float4*>(enc) + (size_t)r * (TWOH / 4);
    float acc = 0.0f;
#pragma unroll
    for (int i = 0; i < 16; ++i) {                   // 16 * 64 lanes * 4 floats = 4096
        const float4 a = e4[i * 64 + lane];
        const float4 b = vs[i * 64 + lane];
        acc += a.x * b.x + a.y * b.y + a.z * b.z + a.w * b.w;
    }
#pragma unroll
    for (int off = 32; off > 0; off >>= 1)
        acc += __shfl_down(acc, off, 64);
    if (lane == 0)
        scores[r] = acc;
}

// ---------------------------------------------------------------------------
// Kernel D: softmax over 8192 scores. One block of 1024 threads,
// 8 elements per thread (strided).
// ---------------------------------------------------------------------------
__global__ __launch_bounds__(1024) void softmax_kernel(
    const float* __restrict__ scores, float* __restrict__ out)
{
    __shared__ float red[16];
    const int t    = threadIdx.x;
    const int wave = t >> 6;
    const int lane = t & 63;

    float x[8];
    float m = -INFINITY;
#pragma unroll
    for (int i = 0; i < 8; ++i) {
        x[i] = scores[t + i * 1024];
        m = fmaxf(m, x[i]);
    }
#pragma unroll
    for (int off = 32; off > 0; off >>= 1)
        m = fmaxf(m, __shfl_down(m, off, 64));
    if (lane == 0) red[wave] = m;
    __syncthreads();
    float gmax = red[0];
#pragma unroll
    for (int w = 1; w < 16; ++w) gmax = fmaxf(gmax, red[w]);
    __syncthreads();                                 // before reusing red[]

    float s = 0.0f;
#pragma unroll
    for (int i = 0; i < 8; ++i) {
        x[i] = expf(x[i] - gmax);
        s += x[i];
    }
#pragma unroll
    for (int off = 32; off > 0; off >>= 1)
        s += __shfl_down(s, off, 64);
    if (lane == 0) red[wave] = s;
    __syncthreads();
    float gsum = 0.0f;
#pragma unroll
    for (int w = 0; w < 16; ++w) gsum += red[w];

    const float inv = 1.0f / gsum;
#pragma unroll
    for (int i = 0; i < 8; ++i)
        out[t + i * 1024] = x[i] * inv;
}

// ---------------------------------------------------------------------------
extern "C" void kernel_launch(void* const* d_in, const int* in_sizes, int n_in,
                              void* d_out, int out_size, void* d_ws, size_t ws_size,
                              hipStream_t stream)
{
    const float* hidden = (const float*)d_in[0];   // [2048]
    const float* enc    = (const float*)d_in[1];   // [8192, 4096]
    const float* W      = (const float*)d_in[2];   // [2048, 4096]
    // d_in[3] = b : irrelevant (softmax shift invariance)

    float* ws      = (float*)d_ws;
    float* partial = ws;                            // 32 * 4096
    float* v       = ws + ROW_CHUNKS * TWOH;        // 4096
    float* scores  = v + TWOH;                      // 8192
    float* out     = (float*)d_out;                 // [8192] fp32

    wtv_partial_kernel<<<dim3(16, ROW_CHUNKS), 256, 0, stream>>>(W, hidden, partial);
    wtv_reduce_kernel<<<16, 256, 0, stream>>>(partial, v);
    scores_kernel<<<SEQLEN / 4, 256, 0, stream>>>(enc, v, scores);
    softmax_kernel<<<1, 1024, 0, stream>>>(scores, out);
}